// Round 5
// baseline (127.270 us; speedup 1.0000x reference)
//
#include <hip/hip_runtime.h>

// CharRNN GRU: B=4096, T=256, V=256, H=20, L=15, reset_after=True, drop_rate=0.
// f32 in / f32 out. 3 batches per wave (20 lanes each); NO barriers and NO LDS
// traffic in the recurrence: h exchanged with ds_bpermute, U pinned in VGPRs,
// dots as float2 pk-FMA. xW gather table in LDS as int2 {bf16 z|r, f32 h}.

#define BB 4096
#define TT 256
#define VV 256
#define HH 20
#define G3 60    // 3*H
#define LL 15
#define NBATCH 12             // batches per block (4 waves x 3)
#define NTHREADS 256

typedef float v2f __attribute__((ext_vector_type(2)));

__device__ __forceinline__ unsigned short f2bf(float f) {
    union { float f; unsigned int i; } c;
    c.f = f;
    unsigned int x = c.i;
    return (unsigned short)((x + 0x7FFFu + ((x >> 16) & 1u)) >> 16); // RNE
}

__device__ __forceinline__ float fast_rcp(float x) {
#if __has_builtin(__builtin_amdgcn_rcpf)
    return __builtin_amdgcn_rcpf(x);
#else
    return 1.0f / x;
#endif
}

__device__ __forceinline__ float fast_sigmoid(float x) {
    return fast_rcp(1.0f + __expf(-x));
}

__device__ __forceinline__ float fast_tanh(float x) {
    return 1.0f - 2.0f * fast_rcp(1.0f + __expf(2.0f * x));
}

// wave-internal broadcast: pull hmine from lane (byteaddr>>2)
__device__ __forceinline__ float bcast(float v, int byteaddr) {
    return __int_as_float(__builtin_amdgcn_ds_bpermute(byteaddr, __float_as_int(v)));
}

__global__ __launch_bounds__(NTHREADS, 2) void gru_kernel(
    const int* __restrict__ x,            // [B][T] int32
    const float* __restrict__ kernelW,    // [V][3H] f32
    const float* __restrict__ rkernel,    // [H][3H] f32
    const float* __restrict__ bias,       // [2][3H] f32
    const float* __restrict__ dense_w,    // [H][L] f32
    const float* __restrict__ dense_b,    // [L] f32
    float* __restrict__ out)              // [B][L] f32
{
    __shared__ int2  xwall[VV * HH];      // {bf16(z)|bf16(r)<<16, f32 h}: 40960 B
    __shared__ float u_lds[HH * G3];      // staging only (read once into VGPRs)
    __shared__ float w_lds[HH * LL];
    __shared__ float db_lds[LL];
    __shared__ int   x_lds[NBATCH][TT + 1];   // +1 pad

    const int tid = threadIdx.x;
    const long b0 = (long)blockIdx.x * NBATCH;

    // ---- staging (one barrier total) ----
    for (int idx = tid; idx < VV * HH; idx += NTHREADS) {
        const int v = idx / HH, j = idx - v * HH;
        const float vz = kernelW[v * G3 + j]          + bias[j];
        const float vr = kernelW[v * G3 + HH + j]     + bias[HH + j];
        const float vh = kernelW[v * G3 + 2 * HH + j] + bias[2 * HH + j];
        int2 pk;
        pk.x = (int)((unsigned)f2bf(vz) | ((unsigned)f2bf(vr) << 16));
        pk.y = __float_as_int(vh);
        xwall[idx] = pk;
    }
    for (int idx = tid; idx < HH * G3; idx += NTHREADS) u_lds[idx] = rkernel[idx];
    for (int idx = tid; idx < HH * LL; idx += NTHREADS) w_lds[idx] = dense_w[idx];
    if (tid < LL) db_lds[tid] = dense_b[tid];
    for (int k = tid; k < NBATCH * TT; k += NTHREADS) {
        const long gi = b0 * TT + k;
        x_lds[k >> 8][k & 255] = (gi < (long)BB * TT) ? x[gi] : 0;
    }
    __syncthreads();   // the ONLY block barrier

    const int lane = tid & 63;
    const int g3   = lane / 20;            // 0..2 active, 3 for idle lanes 60-63
    const int j    = lane - g3 * 20;
    const bool active = (lane < 60);
    const int lb   = (tid >> 6) * 3 + g3;  // local batch
    const int lbc  = active ? lb : 0;
    const int ba   = g3 * 80;              // bpermute byte base of group lane 0

    // recurrent kernel columns j, H+j, 2H+j as float2 pairs over i (60 VGPRs)
    v2f Uz2[10], Ur2[10], Uh2[10];
    #pragma unroll
    for (int q = 0; q < 10; ++q) {
        Uz2[q] = v2f{ u_lds[(2*q) * G3 + j],          u_lds[(2*q+1) * G3 + j] };
        Ur2[q] = v2f{ u_lds[(2*q) * G3 + HH + j],     u_lds[(2*q+1) * G3 + HH + j] };
        Uh2[q] = v2f{ u_lds[(2*q) * G3 + 2*HH + j],   u_lds[(2*q+1) * G3 + 2*HH + j] };
    }
    // pin in VGPRs: forbid re-materialization from LDS inside the loop
    #pragma unroll
    for (int q = 0; q < 10; ++q)
        asm volatile("" : "+v"(Uz2[q]), "+v"(Ur2[q]), "+v"(Uh2[q]));

    const float brz = bias[G3 + j];
    const float brr = bias[G3 + HH + j];
    const float brh = bias[G3 + 2 * HH + j];

    float hmine = 0.0f;
    const int* xrow = x_lds[lbc];

    #pragma unroll 2
    for (int t = 0; t < TT; ++t) {
        const int xv = xrow[t];                      // 3 addrs/wave, broadcast
        const int2 w = xwall[xv * HH + j];           // one ds_read_b64
        const float xz = __uint_as_float(((unsigned)w.x) << 16);
        const float xr = __uint_as_float(((unsigned)w.x) & 0xffff0000u);
        const float xh = __int_as_float(w.y);

        // h broadcast: 20 ds_bpermute (no LDS memory, no ordering semantics)
        v2f hb[10];
        #pragma unroll
        for (int q = 0; q < 10; ++q) {
            hb[q].x = bcast(hmine, ba + 8 * q);
            hb[q].y = bcast(hmine, ba + 8 * q + 4);
        }

        // two packed chains per gate
        v2f za = v2f{brz, 0.f}, ra = v2f{brr, 0.f}, ha = v2f{brh, 0.f};
        v2f zb = v2f{0.f, 0.f}, rb = v2f{0.f, 0.f}, hk = v2f{0.f, 0.f};
        #pragma unroll
        for (int q = 0; q < 5; ++q) {
            za = __builtin_elementwise_fma(hb[q], Uz2[q], za);
            ra = __builtin_elementwise_fma(hb[q], Ur2[q], ra);
            ha = __builtin_elementwise_fma(hb[q], Uh2[q], ha);
        }
        #pragma unroll
        for (int q = 5; q < 10; ++q) {
            zb = __builtin_elementwise_fma(hb[q], Uz2[q], zb);
            rb = __builtin_elementwise_fma(hb[q], Ur2[q], rb);
            hk = __builtin_elementwise_fma(hb[q], Uh2[q], hk);
        }
        const v2f zs = za + zb, rs = ra + rb, hs = ha + hk;
        const float z  = fast_sigmoid(xz + zs.x + zs.y);
        const float r  = fast_sigmoid(xr + rs.x + rs.y);
        const float hc = fast_tanh(fmaf(r, hs.x + hs.y, xh));
        hmine = hc + z * (hmine - hc);
    }

    // final h broadcast for the dense head (registers only, no barrier)
    float hf[HH];
    #pragma unroll
    for (int i = 0; i < HH; ++i) hf[i] = bcast(hmine, ba + 4 * i);

    // ---- dense head: logits[b][l] = db[l] + sum_i h[i] * W[i][l] ----
    const long gb = b0 + lb;
    if (active && j < LL && gb < BB) {
        float acc = db_lds[j];
        #pragma unroll
        for (int i = 0; i < HH; ++i)
            acc = fmaf(hf[i], w_lds[i * LL + j], acc);
        out[gb * LL + j] = acc;
    }
}

extern "C" void kernel_launch(void* const* d_in, const int* in_sizes, int n_in,
                              void* d_out, int out_size, void* d_ws, size_t ws_size,
                              hipStream_t stream) {
    const int* x            = (const int*)d_in[0];
    // d_in[1] = drop_rate (0.0f) -> dropout is identity; ignored.
    const float* kernelW    = (const float*)d_in[2];
    const float* rkernel    = (const float*)d_in[3];
    const float* bias       = (const float*)d_in[4];
    const float* dense_w    = (const float*)d_in[5];
    const float* dense_b    = (const float*)d_in[6];
    float* out              = (float*)d_out;

    dim3 grid((BB + NBATCH - 1) / NBATCH);   // 342 blocks
    dim3 block(NTHREADS);                    // 256 threads = 4 waves = 12 batches
    gru_kernel<<<grid, block, 0, stream>>>(x, kernelW, rkernel, bias,
                                           dense_w, dense_b, out);
}

// Round 6
// 84.040 us; speedup vs baseline: 1.5144x; 1.5144x over previous
//
#include <hip/hip_runtime.h>

// CharRNN GRU: B=4096, T=256, V=256, H=20, L=15, reset_after=True, drop_rate=0.
// f32 in / f32 out. 3 batches per wave (20 lanes each), no block barriers in
// the recurrence. h exchange: one asm block/step (ds_write + 5x ds_read_b128 +
// lgkmcnt(0)) relying on per-wave in-order DS completion — no "memory"
// clobber, so U stays register-resident (launch_bounds(.,1) = 256 VGPR budget)
// and the compiler can prefetch x/xW across iterations.

#define BB 4096
#define TT 256
#define VV 256
#define HH 20
#define G3 60    // 3*H
#define LL 15
#define NBATCH 12             // batches per block (4 waves x 3)
#define NTHREADS 256

typedef float v2f __attribute__((ext_vector_type(2)));
typedef float v4f __attribute__((ext_vector_type(4)));

__device__ __forceinline__ unsigned short f2bf(float f) {
    union { float f; unsigned int i; } c;
    c.f = f;
    unsigned int x = c.i;
    return (unsigned short)((x + 0x7FFFu + ((x >> 16) & 1u)) >> 16); // RNE
}

__device__ __forceinline__ float fast_rcp(float x) {
#if __has_builtin(__builtin_amdgcn_rcpf)
    return __builtin_amdgcn_rcpf(x);
#else
    return 1.0f / x;
#endif
}

__device__ __forceinline__ float fast_sigmoid(float x) {
    return fast_rcp(1.0f + __expf(-x));
}

__device__ __forceinline__ float fast_tanh(float x) {
    return 1.0f - 2.0f * fast_rcp(1.0f + __expf(2.0f * x));
}

// one GRU-step h exchange: write my h, read my group's 20 h values.
// Per-wave DS ops complete in order -> read sees this wave's write.
__device__ __forceinline__ void h_exchange(unsigned waddr, float h, unsigned raddr,
                                           v4f& a0, v4f& a1, v4f& a2, v4f& a3, v4f& a4) {
    asm volatile(
        "ds_write_b32 %6, %7\n\t"
        "ds_read_b128 %0, %5\n\t"
        "ds_read_b128 %1, %5 offset:16\n\t"
        "ds_read_b128 %2, %5 offset:32\n\t"
        "ds_read_b128 %3, %5 offset:48\n\t"
        "ds_read_b128 %4, %5 offset:64\n\t"
        "s_waitcnt lgkmcnt(0)"
        : "=&v"(a0), "=&v"(a1), "=&v"(a2), "=&v"(a3), "=&v"(a4)
        : "v"(raddr), "v"(waddr), "v"(h));
}

__global__ __launch_bounds__(NTHREADS, 1) void gru_kernel(
    const int* __restrict__ x,            // [B][T] int32
    const float* __restrict__ kernelW,    // [V][3H] f32
    const float* __restrict__ rkernel,    // [H][3H] f32
    const float* __restrict__ bias,       // [2][3H] f32
    const float* __restrict__ dense_w,    // [H][L] f32
    const float* __restrict__ dense_b,    // [L] f32
    float* __restrict__ out)              // [B][L] f32
{
    __shared__ int2  xwall[VV * HH];      // {bf16(z)|bf16(r)<<16, f32 h}: 40960 B
    __shared__ float u_lds[HH * G3];      // staging only (read once into VGPRs)
    __shared__ float w_lds[HH * LL];
    __shared__ float db_lds[LL];
    __shared__ int   x_lds[NBATCH][TT + 1];   // +1 pad
    __shared__ float hbuf[NBATCH * HH + 16];  // groups at 80B stride + scratch

    const int tid = threadIdx.x;
    const long b0 = (long)blockIdx.x * NBATCH;

    // ---- staging (one barrier total) ----
    for (int idx = tid; idx < VV * HH; idx += NTHREADS) {
        const int v = idx / HH, j = idx - v * HH;
        const float vz = kernelW[v * G3 + j]          + bias[j];
        const float vr = kernelW[v * G3 + HH + j]     + bias[HH + j];
        const float vh = kernelW[v * G3 + 2 * HH + j] + bias[2 * HH + j];
        int2 pk;
        pk.x = (int)((unsigned)f2bf(vz) | ((unsigned)f2bf(vr) << 16));
        pk.y = __float_as_int(vh);
        xwall[idx] = pk;
    }
    for (int idx = tid; idx < HH * G3; idx += NTHREADS) u_lds[idx] = rkernel[idx];
    for (int idx = tid; idx < HH * LL; idx += NTHREADS) w_lds[idx] = dense_w[idx];
    if (tid < LL) db_lds[tid] = dense_b[tid];
    for (int k = tid; k < NBATCH * TT; k += NTHREADS) {
        const long gi = b0 * TT + k;
        x_lds[k >> 8][k & 255] = (gi < (long)BB * TT) ? x[gi] : 0;
    }
    __syncthreads();   // the ONLY block barrier

    const int lane = tid & 63;
    const int g3   = lane / 20;            // 0..2 active, 3 for idle lanes 60-63
    const int j    = lane - g3 * 20;
    const bool active = (lane < 60);
    const int lb   = (tid >> 6) * 3 + g3;  // local batch
    const int lbc  = active ? lb : 0;
    const int hwidx = active ? (lb * HH + j)
                             : (NBATCH * HH + (tid >> 6) * 4 + (lane - 60));

    const unsigned hbase = (unsigned)(size_t)&hbuf[0];   // LDS byte offset
    const unsigned waddr = hbase + 4u * hwidx;
    const unsigned raddr = hbase + 80u * lbc;

    // recurrent kernel columns j, H+j, 2H+j as float2 pairs over i (60 VGPRs)
    v2f Uz2[10], Ur2[10], Uh2[10];
    #pragma unroll
    for (int q = 0; q < 10; ++q) {
        Uz2[q] = v2f{ u_lds[(2*q) * G3 + j],        u_lds[(2*q+1) * G3 + j] };
        Ur2[q] = v2f{ u_lds[(2*q) * G3 + HH + j],   u_lds[(2*q+1) * G3 + HH + j] };
        Uh2[q] = v2f{ u_lds[(2*q) * G3 + 2*HH + j], u_lds[(2*q+1) * G3 + 2*HH + j] };
    }
    const float brz = bias[G3 + j];
    const float brr = bias[G3 + HH + j];
    const float brh = bias[G3 + 2 * HH + j];

    float hmine = 0.0f;
    const int* xrow = x_lds[lbc];

    #pragma unroll 2
    for (int t = 0; t < TT; ++t) {
        // exchange h(t): write mine, read my group's full vector
        v4f a0, a1, a2, a3, a4;
        h_exchange(waddr, hmine, raddr, a0, a1, a2, a3, a4);
        v2f hb[10];
        hb[0] = v2f{a0.x, a0.y}; hb[1] = v2f{a0.z, a0.w};
        hb[2] = v2f{a1.x, a1.y}; hb[3] = v2f{a1.z, a1.w};
        hb[4] = v2f{a2.x, a2.y}; hb[5] = v2f{a2.z, a2.w};
        hb[6] = v2f{a3.x, a3.y}; hb[7] = v2f{a3.z, a3.w};
        hb[8] = v2f{a4.x, a4.y}; hb[9] = v2f{a4.z, a4.w};

        const int xv = xrow[t];                      // 3 addrs/wave, broadcast
        const int2 w = xwall[xv * HH + j];           // one ds_read_b64
        const float xz = __uint_as_float(((unsigned)w.x) << 16);
        const float xr = __uint_as_float(((unsigned)w.x) & 0xffff0000u);
        const float xh = __int_as_float(w.y);

        // two packed chains per gate (v_pk_fma_f32)
        v2f za = v2f{brz, 0.f}, ra = v2f{brr, 0.f}, ha = v2f{brh, 0.f};
        v2f zb = v2f{0.f, 0.f}, rb = v2f{0.f, 0.f}, hk = v2f{0.f, 0.f};
        #pragma unroll
        for (int q = 0; q < 5; ++q) {
            za = __builtin_elementwise_fma(hb[q], Uz2[q], za);
            ra = __builtin_elementwise_fma(hb[q], Ur2[q], ra);
            ha = __builtin_elementwise_fma(hb[q], Uh2[q], ha);
        }
        #pragma unroll
        for (int q = 5; q < 10; ++q) {
            zb = __builtin_elementwise_fma(hb[q], Uz2[q], zb);
            rb = __builtin_elementwise_fma(hb[q], Ur2[q], rb);
            hk = __builtin_elementwise_fma(hb[q], Uh2[q], hk);
        }
        const v2f zs = za + zb, rs = ra + rb, hs = ha + hk;
        const float z  = fast_sigmoid(xz + zs.x + zs.y);
        const float r  = fast_sigmoid(xr + rs.x + rs.y);
        const float hc = fast_tanh(fmaf(r, hs.x + hs.y, xh));
        hmine = hc + z * (hmine - hc);
    }

    // final exchange to collect h(T) for the dense head
    v4f a0, a1, a2, a3, a4;
    h_exchange(waddr, hmine, raddr, a0, a1, a2, a3, a4);
    const float hf[HH] = { a0.x,a0.y,a0.z,a0.w, a1.x,a1.y,a1.z,a1.w,
                           a2.x,a2.y,a2.z,a2.w, a3.x,a3.y,a3.z,a3.w,
                           a4.x,a4.y,a4.z,a4.w };

    // ---- dense head: logits[b][l] = db[l] + sum_i h[i] * W[i][l] ----
    const long gb = b0 + lb;
    if (active && j < LL && gb < BB) {
        float acc = db_lds[j];
        #pragma unroll
        for (int i = 0; i < HH; ++i)
            acc = fmaf(hf[i], w_lds[i * LL + j], acc);
        out[gb * LL + j] = acc;
    }
}

extern "C" void kernel_launch(void* const* d_in, const int* in_sizes, int n_in,
                              void* d_out, int out_size, void* d_ws, size_t ws_size,
                              hipStream_t stream) {
    const int* x            = (const int*)d_in[0];
    // d_in[1] = drop_rate (0.0f) -> dropout is identity; ignored.
    const float* kernelW    = (const float*)d_in[2];
    const float* rkernel    = (const float*)d_in[3];
    const float* bias       = (const float*)d_in[4];
    const float* dense_w    = (const float*)d_in[5];
    const float* dense_b    = (const float*)d_in[6];
    float* out              = (float*)d_out;

    dim3 grid((BB + NBATCH - 1) / NBATCH);   // 342 blocks
    dim3 block(NTHREADS);                    // 256 threads = 4 waves = 12 batches
    gru_kernel<<<grid, block, 0, stream>>>(x, kernelW, rkernel, bias,
                                           dense_w, dense_b, out);
}